// Round 6
// baseline (821.626 us; speedup 1.0000x reference)
//
#include <hip/hip_runtime.h>
#include <stdint.h>

#define D 128

typedef unsigned int u32;
typedef unsigned short u16;
typedef __attribute__((ext_vector_type(8))) short short8;  // 8 bf16 bit-patterns (4 VGPRs)
typedef __attribute__((ext_vector_type(4))) float f32x4;

static __device__ __forceinline__ float bf2f(u16 h) {
    return __uint_as_float(((u32)h) << 16);
}
static __device__ __forceinline__ u16 f2bf(float f) {
    u32 u = __float_as_uint(f);
    u32 r = (u + 0x7fffu + ((u >> 16) & 1u)) >> 16;  // round-to-nearest-even
    return (u16)r;
}
static __device__ __forceinline__ int clampi(int v, int n) {
    if (v < 0) v = 0;
    if (v >= n) v = n - 1;
    return v;
}

// ---------------- init: zero hist/csr_pos + dtype probe (block 0, wave 0) ----------------
// flags[0]=1 item_emb/biases bf16 else fp32; flags[1]=1 edges int64 else int32;
// flags[2]=1 weights bf16 else fp32
__global__ void k_init(int* __restrict__ hist, int* __restrict__ csr_pos, int n,
                       const u16* __restrict__ emb_raw, const u32* __restrict__ ei_raw,
                       const u16* __restrict__ w_raw, int* __restrict__ flags) {
    int i = blockIdx.x * 256 + threadIdx.x;
    if (i < n) {
        hist[i] = 0;
        csr_pos[i] = 0;
    }
    if (blockIdx.x == 0 && threadIdx.x < 64) {
        int t = threadIdx.x;
        int se = 0, sw = 0, zz = 0;
#pragma unroll
        for (int q = 0; q < 4; q++) {
            int k = t * 4 + q;  // 256 samples
            u16 he = emb_raw[2 * k];
            u32 exe = (he >> 7) & 0xFF;
            if (he == 0 || (exe >= 0x60 && exe <= 0x8F)) se++;
            u16 hw = w_raw[2 * k];
            u32 exw = (hw >> 7) & 0xFF;
            if (hw == 0 || (exw >= 0x60 && exw <= 0x8F)) sw++;
            if (ei_raw[2 * k + 1] == 0) zz++;
        }
#pragma unroll
        for (int o = 32; o; o >>= 1) {
            se += __shfl_down(se, o);
            sw += __shfl_down(sw, o);
            zz += __shfl_down(zz, o);
        }
        if (t == 0) {
            flags[0] = (se >= 200) ? 1 : 0;
            flags[2] = (sw >= 200) ? 1 : 0;
            flags[1] = (zz >= 200) ? 1 : 0;
        }
    }
}

// ---------------- fused: degree histogram (blocks [0,eb)) + W-prep (blocks [eb,eb+192)) ----
// W -> MFMA B-fragment layout, split-bf16 (hi + lo residual).
// B-frag for mfma_f32_16x16x32_bf16: lane l holds W[k = ks*32 + (l>>4)*8 + e][j = c*16 + (l&15)],
// e = 0..7.  WB layout (u16): [layer][h(hi/lo)][c(8)][ks(4)][lane(64)][e(8)]  => 64 KB / layer.
__global__ void k_hw(const u32* __restrict__ ei, int E, int n,
                     const int* __restrict__ flags, int* __restrict__ hist,
                     const void* __restrict__ Wbase, u16* __restrict__ WB, int eb) {
    int bid = blockIdx.x;
    if (bid < eb) {
        int e = bid * 256 + threadIdx.x;
        if (e >= E) return;
        int d;
        if (flags[1]) d = ((const int2*)ei)[(size_t)E + e].x;  // int64: low word
        else          d = (int)ei[(size_t)E + e];
        atomicAdd(&hist[clampi(d, n)], 1);
    } else {
        int idx = (bid - eb) * 256 + threadIdx.x;  // [0, 3*16384)
        int e = idx & 7;
        int l = (idx >> 3) & 63;
        int ks = (idx >> 9) & 3;
        int c = (idx >> 11) & 7;
        int layer = idx >> 14;
        int k = ks * 32 + ((l >> 4) << 3) + e;
        int j = (c << 4) + (l & 15);
        size_t src = (size_t)layer * D * D + (size_t)k * D + j;
        float w = flags[2] ? bf2f(((const u16*)Wbase)[src]) : ((const float*)Wbase)[src];
        u16 hb = f2bf(w);
        u16 lb = f2bf(w - bf2f(hb));  // residual: Wh+Wl represents w to ~2^-17
        size_t o = (size_t)layer * 32768 + (size_t)((c * 4 + ks) * 64 + l) * 8 + e;
        WB[o] = hb;            // h=0 (hi)
        WB[o + 16384] = lb;    // h=1 (lo)
    }
}

// ---------------- scan1: per-block inclusive scan ----------------
__global__ void k_scan1(const int* __restrict__ hist, int n,
                        int* __restrict__ incl, int* __restrict__ bsums) {
    __shared__ int s[256];
    int t = threadIdx.x;
    int i = blockIdx.x * 256 + t;
    int v = (i < n) ? hist[i] : 0;
    s[t] = v;
    __syncthreads();
    for (int d2 = 1; d2 < 256; d2 <<= 1) {
        int add = (t >= d2) ? s[t - d2] : 0;
        __syncthreads();
        s[t] += add;
        __syncthreads();
    }
    if (i < n) incl[i] = s[t];
    if (t == 255) bsums[blockIdx.x] = s[255];
}

// ---------------- scan23: each block reduces its own bsums prefix, finalizes ----------------
__global__ void k_scan23(const int* __restrict__ hist, const int* __restrict__ bsums,
                         int n, int* __restrict__ csr_off, float* __restrict__ dinv) {
    __shared__ int s[256];
    int t = threadIdx.x, b = blockIdx.x;
    s[t] = (t < b) ? bsums[t] : 0;  // t<b<nb so in-bounds
    __syncthreads();
    for (int o = 128; o; o >>= 1) {
        if (t < o) s[t] += s[t + o];
        __syncthreads();
    }
    int add = s[0];
    int i = b * 256 + t;
    if (i < n) {
        int h = hist[i];
        csr_off[i] = add + csr_off[i] - h;  // incl -> excl + block offset
        dinv[i] = rsqrtf((float)(h + 1));   // +1 self-loop
    }
}

// ---------------- fused scatter (blocks [0,eb)) + x0 copy (blocks [eb,..)) ----------------
__global__ void k_sx(const u32* __restrict__ ei, int E, int n,
                     const int* __restrict__ flags,
                     const int* __restrict__ csr_off, int* __restrict__ csr_pos,
                     const float* __restrict__ dinv, int2* __restrict__ csr_pair,
                     const void* __restrict__ emb, int off_elems, int nD4,
                     float* __restrict__ out_x0, int eb) {
    int bid = blockIdx.x;
    if (bid < eb) {
        int e = bid * 256 + threadIdx.x;
        if (e >= E) return;
        int s, d;
        if (flags[1]) {
            s = ((const int2*)ei)[e].x;
            d = ((const int2*)ei)[(size_t)E + e].x;
        } else {
            s = (int)ei[e];
            d = (int)ei[(size_t)E + e];
        }
        s = clampi(s, n);
        d = clampi(d, n);
        int p = csr_off[d] + atomicAdd(&csr_pos[d], 1);
        if (p >= E) p = E - 1;
        csr_pair[p] = make_int2(s, __float_as_int(dinv[s] * dinv[d]));
    } else {
        int i = (bid - eb) * 256 + threadIdx.x;
        if (i >= nD4) return;
        float4 v;
        if (flags[0]) {
            ushort4 h = ((const ushort4*)((const u16*)emb + off_elems))[i];
            v = make_float4(bf2f(h.x), bf2f(h.y), bf2f(h.z), bf2f(h.w));
        } else {
            v = ((const float4*)((const float*)emb + off_elems))[i];
        }
        ((float4*)out_x0)[i] = v;
    }
}

// ---------------- GEMM: Y(bf16-packed) = A(fp32) @ W_l   via split-bf16 MFMA ----------------
__global__ __launch_bounds__(256) void k_gemm(const float* __restrict__ A,
                                              const u16* __restrict__ WB, int layer,
                                              int n, u32* __restrict__ Y) {
    __shared__ f32x4 ldsv[4096];  // 64 KB: WB[layer] verbatim
    int tid = threadIdx.x;
    {
        const f32x4* src = (const f32x4*)(WB + (size_t)layer * 32768);
#pragma unroll
        for (int i = 0; i < 16; i++) ldsv[tid + 256 * i] = src[tid + 256 * i];
    }
    __syncthreads();

    int w = tid >> 6, l = tid & 63;
    int row0 = blockIdx.x * 64 + w * 16;
    int ar = row0 + (l & 15);
    if (ar >= n) ar = 0;  // OOB rows read row 0; masked at store
    const float* Ab = A + (size_t)ar * D + ((l >> 4) << 3);

    f32x4 acc[8] = {};
    const short8* bp = (const short8*)ldsv;

#pragma unroll
    for (int ks = 0; ks < 4; ks++) {
        f32x4 a0 = *(const f32x4*)(Ab + ks * 32);
        f32x4 a1 = *(const f32x4*)(Ab + ks * 32 + 4);
        float av[8] = {a0.x, a0.y, a0.z, a0.w, a1.x, a1.y, a1.z, a1.w};
        short8 ah, al;
#pragma unroll
        for (int e = 0; e < 8; e++) {
            u16 h = f2bf(av[e]);
            ah[e] = (short)h;
            al[e] = (short)f2bf(av[e] - bf2f(h));
        }
#pragma unroll
        for (int c = 0; c < 8; c++) {
            short8 bh = bp[(c * 4 + ks) * 64 + l];
            short8 bl = bp[2048 + (c * 4 + ks) * 64 + l];
            acc[c] = __builtin_amdgcn_mfma_f32_16x16x32_bf16(al, bh, acc[c], 0, 0, 0);
            acc[c] = __builtin_amdgcn_mfma_f32_16x16x32_bf16(ah, bl, acc[c], 0, 0, 0);
            acc[c] = __builtin_amdgcn_mfma_f32_16x16x32_bf16(ah, bh, acc[c], 0, 0, 0);
        }
    }

    int rbase = row0 + ((l >> 4) << 2);
    int col = l & 15;
#pragma unroll
    for (int r = 0; r < 4; r++) {
        int gr = rbase + r;
        if (gr < n) {
#pragma unroll
            for (int c = 0; c < 4; c++) {
                u32 pack = (u32)f2bf(acc[c][r]) | ((u32)f2bf(acc[c + 4][r]) << 16);
                Y[(size_t)gr * 64 + c * 16 + col] = pack;
            }
        }
    }
}

// ---------------- aggregation: one WAVE per dst node; 4 edges per gather instr ----------------
__global__ __launch_bounds__(256) void k_agg(const u32* __restrict__ Y,
                                             const int* __restrict__ csr_off,
                                             const int* __restrict__ cnt,
                                             const int2* __restrict__ csr_pair,
                                             const float* __restrict__ dinv,
                                             const void* __restrict__ bias_base, int layer,
                                             const int* __restrict__ flags, int n, int nD,
                                             const float* __restrict__ out_base,
                                             float* __restrict__ out_x,
                                             float* __restrict__ out_tot) {
    int i = blockIdx.x * 4 + (threadIdx.x >> 6);
    if (i >= n) return;
    int t = threadIdx.x & 63;
    int g = t >> 4, p = t & 15;

    float lo0 = 0.f, lo1 = 0.f, lo2 = 0.f, lo3 = 0.f;
    float hi0 = 0.f, hi1 = 0.f, hi2 = 0.f, hi3 = 0.f;

#define ACC4(V, W)                                                       \
    do {                                                                 \
        lo0 += __uint_as_float((V).x << 16) * (W);                       \
        hi0 += __uint_as_float((V).x & 0xffff0000u) * (W);               \
        lo1 += __uint_as_float((V).y << 16) * (W);                       \
        hi1 += __uint_as_float((V).y & 0xffff0000u) * (W);               \
        lo2 += __uint_as_float((V).z << 16) * (W);                       \
        hi2 += __uint_as_float((V).z & 0xffff0000u) * (W);               \
        lo3 += __uint_as_float((V).w << 16) * (W);                       \
        hi3 += __uint_as_float((V).w & 0xffff0000u) * (W);               \
    } while (0)

    float di = dinv[i];
    {
        uint4 vs = *(const uint4*)(Y + (size_t)i * 64 + p * 4);
        float ws = (g == 0) ? di * di : 0.0f;
        ACC4(vs, ws);
    }

    int start = csr_off[i];
    int c = cnt[i];

    for (int base = 0; base < c; base += 64) {
        int m = c - base;
        if (m > 64) m = 64;
        int2 pr = (t < m) ? csr_pair[start + base + t] : make_int2(0, 0);
        int s0 = __shfl(pr.x, g);
        float w0 = __uint_as_float((u32)__shfl(pr.y, g));
        uint4 v0 = *(const uint4*)(Y + (size_t)s0 * 64 + p * 4);
        for (int j = 4; j < m; j += 4) {
            int s1 = __shfl(pr.x, j + g);
            float w1 = __uint_as_float((u32)__shfl(pr.y, j + g));
            uint4 v1 = *(const uint4*)(Y + (size_t)s1 * 64 + p * 4);
            ACC4(v0, w0);
            v0 = v1;
            w0 = w1;
        }
        ACC4(v0, w0);
    }
#undef ACC4

#pragma unroll
    for (int mask = 16; mask <= 32; mask <<= 1) {
        lo0 += __shfl_xor(lo0, mask);
        lo1 += __shfl_xor(lo1, mask);
        lo2 += __shfl_xor(lo2, mask);
        lo3 += __shfl_xor(lo3, mask);
        hi0 += __shfl_xor(hi0, mask);
        hi1 += __shfl_xor(hi1, mask);
        hi2 += __shfl_xor(hi2, mask);
        hi3 += __shfl_xor(hi3, mask);
    }

    if (g < 2) {  // g==0: dims 4p..4p+3 ; g==1: dims 64+4p..64+4p+3
        float r0 = g ? hi0 : lo0;
        float r1 = g ? hi1 : lo1;
        float r2 = g ? hi2 : lo2;
        float r3 = g ? hi3 : lo3;
        int off = g * 64 + 4 * p;
        float b0, b1, b2, b3;
        if (flags[0]) {
            const u16* bb = (const u16*)bias_base + layer * D + off;
            ushort4 h = *(const ushort4*)bb;
            b0 = bf2f(h.x); b1 = bf2f(h.y); b2 = bf2f(h.z); b3 = bf2f(h.w);
        } else {
            const float* bb = (const float*)bias_base + layer * D + off;
            float4 f = *(const float4*)bb;
            b0 = f.x; b1 = f.y; b2 = f.z; b3 = f.w;
        }
        float4 xv = make_float4(r0 + b0, r1 + b1, r2 + b2, r3 + b3);
        size_t base = (size_t)i * D + off;
        *(float4*)&out_x[base] = xv;

        if (out_tot) {  // layer 2: fuse total = x0+x1+x2+x3
            float4 s0 = *(const float4*)&out_base[(size_t)1 * nD + base];
            float4 s1 = *(const float4*)&out_base[(size_t)2 * nD + base];
            float4 s2 = *(const float4*)&out_base[(size_t)3 * nD + base];
            *(float4*)&out_tot[base] =
                make_float4(s0.x + s1.x + s2.x + xv.x, s0.y + s1.y + s2.y + xv.y,
                            s0.z + s1.z + s2.z + xv.z, s0.w + s1.w + s2.w + xv.w);
        }
    }
}

// ================== MEASUREMENT PROBES (write scratch only; rep-looped) ==================
// Clones of the real kernels with an outer rep loop so their durations exceed the ~73 us
// harness poison-fills and surface in rocprof top-5 with full counters.

__global__ void k_nop_probe(int* p) {
    if (p) *p = threadIdx.x;
}

__global__ void k_sx_probe(const u32* __restrict__ ei, int E, int n,
                           const int* __restrict__ flags,
                           const int* __restrict__ csr_off, int* __restrict__ csr_pos,
                           const float* __restrict__ dinv, int2* __restrict__ pair2,
                           const void* __restrict__ emb, int off_elems, int nD4,
                           float* __restrict__ xscr, int eb, int rep) {
    for (int r = 0; r < rep; r++) {
        int bid = blockIdx.x;
        if (bid < eb) {
            int e = bid * 256 + threadIdx.x;
            if (e < E) {
                int s, d;
                if (flags[1]) {
                    s = ((const int2*)ei)[e].x;
                    d = ((const int2*)ei)[(size_t)E + e].x;
                } else {
                    s = (int)ei[e];
                    d = (int)ei[(size_t)E + e];
                }
                s = clampi(s, n);
                d = clampi(d, n);
                int p = csr_off[d] + atomicAdd(&csr_pos[d], 1);
                if (p >= E) p = E - 1;
                if (p < 0) p = 0;
                pair2[p] = make_int2(s, __float_as_int(dinv[s] * dinv[d]));
            }
        } else {
            int i = (bid - eb) * 256 + threadIdx.x;
            if (i < nD4) {
                float4 v;
                if (flags[0]) {
                    ushort4 h = ((const ushort4*)((const u16*)emb + off_elems))[i];
                    v = make_float4(bf2f(h.x), bf2f(h.y), bf2f(h.z), bf2f(h.w));
                } else {
                    v = ((const float4*)((const float*)emb + off_elems))[i];
                }
                ((float4*)xscr)[i] = v;
            }
        }
    }
}

__global__ __launch_bounds__(256) void k_gemm_probe(const float* __restrict__ A,
                                                    const u16* __restrict__ WB, int layer,
                                                    int n, u32* __restrict__ Y, int rep) {
    __shared__ f32x4 ldsv[4096];
    int tid = threadIdx.x;
    {
        const f32x4* src = (const f32x4*)(WB + (size_t)layer * 32768);
#pragma unroll
        for (int i = 0; i < 16; i++) ldsv[tid + 256 * i] = src[tid + 256 * i];
    }
    __syncthreads();
    for (int r = 0; r < rep; r++) {
        int w = tid >> 6, l = tid & 63;
        int row0 = blockIdx.x * 64 + w * 16;
        int ar = row0 + (l & 15);
        if (ar >= n) ar = 0;
        const float* Ab = A + (size_t)ar * D + ((l >> 4) << 3);
        f32x4 acc[8] = {};
        const short8* bp = (const short8*)ldsv;
#pragma unroll
        for (int ks = 0; ks < 4; ks++) {
            f32x4 a0 = *(const f32x4*)(Ab + ks * 32);
            f32x4 a1 = *(const f32x4*)(Ab + ks * 32 + 4);
            float av[8] = {a0.x, a0.y, a0.z, a0.w, a1.x, a1.y, a1.z, a1.w};
            short8 ah, al;
#pragma unroll
            for (int e = 0; e < 8; e++) {
                u16 h = f2bf(av[e]);
                ah[e] = (short)h;
                al[e] = (short)f2bf(av[e] - bf2f(h));
            }
#pragma unroll
            for (int c = 0; c < 8; c++) {
                short8 bh = bp[(c * 4 + ks) * 64 + l];
                short8 bl = bp[2048 + (c * 4 + ks) * 64 + l];
                acc[c] = __builtin_amdgcn_mfma_f32_16x16x32_bf16(al, bh, acc[c], 0, 0, 0);
                acc[c] = __builtin_amdgcn_mfma_f32_16x16x32_bf16(ah, bl, acc[c], 0, 0, 0);
                acc[c] = __builtin_amdgcn_mfma_f32_16x16x32_bf16(ah, bh, acc[c], 0, 0, 0);
            }
        }
        int rbase = row0 + ((l >> 4) << 2);
        int col = l & 15;
#pragma unroll
        for (int rr = 0; rr < 4; rr++) {
            int gr = rbase + rr;
            if (gr < n) {
#pragma unroll
                for (int c = 0; c < 4; c++) {
                    u32 pack = (u32)f2bf(acc[c][rr]) | ((u32)f2bf(acc[c + 4][rr]) << 16);
                    Y[(size_t)gr * 64 + c * 16 + col] = pack;
                }
            }
        }
    }
}

__global__ __launch_bounds__(256) void k_agg_probe(const u32* __restrict__ Y,
                                                   const int* __restrict__ csr_off,
                                                   const int* __restrict__ cnt,
                                                   const int2* __restrict__ csr_pair,
                                                   const float* __restrict__ dinv,
                                                   const void* __restrict__ bias_base,
                                                   int layer, const int* __restrict__ flags,
                                                   int n, float* __restrict__ out_x,
                                                   int rep) {
    int i = blockIdx.x * 4 + (threadIdx.x >> 6);
    if (i >= n) return;
    int t = threadIdx.x & 63;
    int g = t >> 4, p = t & 15;

    for (int r = 0; r < rep; r++) {
        float lo0 = 0.f, lo1 = 0.f, lo2 = 0.f, lo3 = 0.f;
        float hi0 = 0.f, hi1 = 0.f, hi2 = 0.f, hi3 = 0.f;

#define ACC4(V, W)                                                       \
    do {                                                                 \
        lo0 += __uint_as_float((V).x << 16) * (W);                       \
        hi0 += __uint_as_float((V).x & 0xffff0000u) * (W);               \
        lo1 += __uint_as_float((V).y << 16) * (W);                       \
        hi1 += __uint_as_float((V).y & 0xffff0000u) * (W);               \
        lo2 += __uint_as_float((V).z << 16) * (W);                       \
        hi2 += __uint_as_float((V).z & 0xffff0000u) * (W);               \
        lo3 += __uint_as_float((V).w << 16) * (W);                       \
        hi3 += __uint_as_float((V).w & 0xffff0000u) * (W);               \
    } while (0)

        float di = dinv[i];
        {
            uint4 vs = *(const uint4*)(Y + (size_t)i * 64 + p * 4);
            float ws = (g == 0) ? di * di : 0.0f;
            ACC4(vs, ws);
        }
        int start = csr_off[i];
        int c = cnt[i];
        for (int base = 0; base < c; base += 64) {
            int m = c - base;
            if (m > 64) m = 64;
            int2 pr = (t < m) ? csr_pair[start + base + t] : make_int2(0, 0);
            int s0 = __shfl(pr.x, g);
            float w0 = __uint_as_float((u32)__shfl(pr.y, g));
            uint4 v0 = *(const uint4*)(Y + (size_t)s0 * 64 + p * 4);
            for (int j = 4; j < m; j += 4) {
                int s1 = __shfl(pr.x, j + g);
                float w1 = __uint_as_float((u32)__shfl(pr.y, j + g));
                uint4 v1 = *(const uint4*)(Y + (size_t)s1 * 64 + p * 4);
                ACC4(v0, w0);
                v0 = v1;
                w0 = w1;
            }
            ACC4(v0, w0);
        }
#undef ACC4

#pragma unroll
        for (int mask = 16; mask <= 32; mask <<= 1) {
            lo0 += __shfl_xor(lo0, mask);
            lo1 += __shfl_xor(lo1, mask);
            lo2 += __shfl_xor(lo2, mask);
            lo3 += __shfl_xor(lo3, mask);
            hi0 += __shfl_xor(hi0, mask);
            hi1 += __shfl_xor(hi1, mask);
            hi2 += __shfl_xor(hi2, mask);
            hi3 += __shfl_xor(hi3, mask);
        }

        if (g < 2) {
            float r0 = g ? hi0 : lo0;
            float r1 = g ? hi1 : lo1;
            float r2 = g ? hi2 : lo2;
            float r3 = g ? hi3 : lo3;
            int off = g * 64 + 4 * p;
            float b0, b1, b2, b3;
            if (flags[0]) {
                const u16* bb = (const u16*)bias_base + layer * D + off;
                ushort4 h = *(const ushort4*)bb;
                b0 = bf2f(h.x); b1 = bf2f(h.y); b2 = bf2f(h.z); b3 = bf2f(h.w);
            } else {
                const float* bb = (const float*)bias_base + layer * D + off;
                float4 f = *(const float4*)bb;
                b0 = f.x; b1 = f.y; b2 = f.z; b3 = f.w;
            }
            float4 xv = make_float4(r0 + b0, r1 + b1, r2 + b2, r3 + b3);
            *(float4*)&out_x[(size_t)i * D + off] = xv;
        }
    }
}

extern "C" void kernel_launch(void* const* d_in, const int* in_sizes, int n_in,
                              void* d_out, int out_size, void* d_ws, size_t ws_size,
                              hipStream_t stream) {
    float* out = (float*)d_out;              // fp32: [total, x0, x1, x2, x3]

    const int n = out_size / (5 * D);        // 50000

    // inputs identified by element count (robust to ordering)
    int i_emb = -1, i_ei = -1, i_w = -1, i_b = -1;
    {
        int order[8];
        int m = n_in > 8 ? 8 : n_in;
        for (int i = 0; i < m; i++) order[i] = i;
        for (int a = 0; a < m; a++)
            for (int b2 = a + 1; b2 < m; b2++)
                if (in_sizes[order[b2]] > in_sizes[order[a]]) {
                    int tmp = order[a]; order[a] = order[b2]; order[b2] = tmp;
                }
        i_emb = order[0];
        i_ei  = (m > 1) ? order[1] : 0;
        for (int i = 0; i < m; i++) {
            if (in_sizes[i] == 3 * D * D && i_w < 0) i_w = i;
            if (in_sizes[i] == 3 * D && i_b < 0) i_b = i;
        }
        if (i_w < 0) i_w = (m > 2) ? order[2] : 0;
        if (i_b < 0) i_b = (m > 3) ? order[3] : 0;
    }
    const void* emb  = d_in[i_emb];
    const void* wts  = d_in[i_w];
    const void* bias = d_in[i_b];
    const u32*  ei   = (const u32*)d_in[i_ei];

    const int E = in_sizes[i_ei] / 2;        // 600000
    const int rows = in_sizes[i_emb] / D;    // 80000
    const int off_elems = (rows - n) * D;

    char* p = (char*)d_ws;
    auto take = [&](size_t bytes) {
        char* r = p;
        p += (bytes + 255) & ~(size_t)255;
        return r;
    };
    int*   flags    = (int*)  take(3 * 4);
    int*   hist     = (int*)  take((size_t)n * 4);
    int*   csr_pos  = (int*)  take((size_t)n * 4);
    int*   csr_off  = (int*)  take((size_t)n * 4);
    int*   bsums    = (int*)  take(256 * 4);
    float* dinv     = (float*)take((size_t)n * 4);
    int2*  csr_pair = (int2*) take((size_t)E * 8);
    u32*   ybuf     = (u32*)  take((size_t)n * 64 * 4);   // bf16-packed Y
    u16*   wb       = (u16*)  take((size_t)3 * 32768 * 2); // W in MFMA B-frag layout (hi+lo)
    // scratch for probes
    float* xscr     = (float*)take((size_t)n * D * 4);
    u32*   yscr     = (u32*)  take((size_t)n * 64 * 4);
    int2*  pair2    = (int2*) take((size_t)E * 8);

    const int nD = n * D;
    const int nb = (n + 255) / 256;          // 196 (<=256 required by scan23)
    const int eb = (E + 255) / 256;
    const int x0b = (nD / 4 + 255) / 256;

    k_init<<<nb, 256, 0, stream>>>(hist, csr_pos, n, (const u16*)emb, ei,
                                   (const u16*)wts, flags);
    k_hw<<<eb + 192, 256, 0, stream>>>(ei, E, n, flags, hist, wts, wb, eb);
    k_scan1<<<nb, 256, 0, stream>>>(hist, n, csr_off, bsums);
    k_scan23<<<nb, 256, 0, stream>>>(hist, bsums, n, csr_off, dinv);
    k_sx<<<eb + x0b, 256, 0, stream>>>(ei, E, n, flags, csr_off, csr_pos, dinv,
                                       csr_pair, emb, off_elems, nD / 4,
                                       out + (size_t)nD, eb);

    const int ab = (n + 3) / 4;  // 4 nodes (waves) per 256-thr block
    for (int l = 0; l < 3; l++) {
        const float* A = out + (size_t)(1 + l) * nD;   // x_l slot (fp32)
        float* ox = out + (size_t)(2 + l) * nD;        // x_{l+1} slot
        k_gemm<<<(n + 63) / 64, 256, 0, stream>>>(A, wb, l, n, ybuf);
        k_agg<<<ab, 256, 0, stream>>>(ybuf, csr_off, hist, csr_pair, dinv, bias, l,
                                      flags, n, nD, out, ox,
                                      (l == 2) ? out : (float*)nullptr);
    }

    // ---- measurement probes (scratch only; surface in rocprof top-5) ----
    k_sx_probe<<<eb + x0b, 256, 0, stream>>>(ei, E, n, flags, csr_off, csr_pos, dinv,
                                             pair2, emb, off_elems, nD / 4, xscr, eb, 8);
    k_gemm_probe<<<(n + 63) / 64, 256, 0, stream>>>(out + (size_t)nD, wb, 0, n, yscr, 16);
    k_agg_probe<<<ab, 256, 0, stream>>>(ybuf, csr_off, hist, csr_pair, dinv, bias, 0,
                                        flags, n, xscr, 8);
    for (int q = 0; q < 20; q++) k_nop_probe<<<1, 64, 0, stream>>>((int*)nullptr);
}

// Round 7
// 378.519 us; speedup vs baseline: 2.1706x; 2.1706x over previous
//
#include <hip/hip_runtime.h>
#include <stdint.h>

#define D 128

typedef unsigned int u32;
typedef unsigned short u16;
typedef __attribute__((ext_vector_type(8))) short short8;  // 8 bf16 bit-patterns (4 VGPRs)
typedef __attribute__((ext_vector_type(4))) float f32x4;

static __device__ __forceinline__ float bf2f(u16 h) {
    return __uint_as_float(((u32)h) << 16);
}
static __device__ __forceinline__ u16 f2bf(float f) {
    u32 u = __float_as_uint(f);
    u32 r = (u + 0x7fffu + ((u >> 16) & 1u)) >> 16;  // round-to-nearest-even
    return (u16)r;
}
static __device__ __forceinline__ int clampi(int v, int n) {
    if (v < 0) v = 0;
    if (v >= n) v = n - 1;
    return v;
}
static __device__ __forceinline__ int bf_plausible(u16 h) {
    u32 ex = (h >> 7) & 0xFF;
    return (h == 0 || (ex >= 0x60 && ex <= 0x8F)) ? 1 : 0;
}

// ============ k_init: zeros + flags (blocks [0,nbk)) + x0 copy (blocks [nbk,..)) ============
// x0-copy blocks use a block-local emb dtype probe (no dependency on flags).
__global__ __launch_bounds__(256) void k_init(int* __restrict__ hist, int* __restrict__ csr_pos,
                                              u32* __restrict__ state, int n, int nbk,
                                              const u16* __restrict__ emb16,
                                              const u32* __restrict__ ei,
                                              const u16* __restrict__ w16,
                                              int* __restrict__ flags,
                                              int off_elems, int nD4,
                                              float* __restrict__ out_x0) {
    int bid = blockIdx.x, t = threadIdx.x;
    if (bid < nbk) {
        int i = bid * 256 + t;
        if (i < n) {
            hist[i] = 0;
            csr_pos[i] = 0;
        }
        if (i < nbk) state[i] = 0;
        if (bid == 0 && t < 64) {
            int se = 0, sw = 0, zz = 0;
#pragma unroll
            for (int q = 0; q < 4; q++) {
                int k = t * 4 + q;  // 256 samples
                se += bf_plausible(emb16[2 * k]);
                sw += bf_plausible(w16[2 * k]);
                if (ei[2 * k + 1] == 0) zz++;
            }
#pragma unroll
            for (int o = 32; o; o >>= 1) {
                se += __shfl_down(se, o);
                sw += __shfl_down(sw, o);
                zz += __shfl_down(zz, o);
            }
            if (t == 0) {
                flags[0] = (se >= 200) ? 1 : 0;
                flags[2] = (sw >= 200) ? 1 : 0;
                flags[1] = (zz >= 200) ? 1 : 0;
            }
        }
    } else {
        __shared__ int ps[256];
        ps[t] = bf_plausible(emb16[2 * t]);
        __syncthreads();
        for (int o = 128; o; o >>= 1) {
            if (t < o) ps[t] += ps[t + o];
            __syncthreads();
        }
        int ef = (ps[0] >= 200);
        int i = (bid - nbk) * 256 + t;
        if (i < nD4) {
            float4 v;
            if (ef) {
                ushort4 h = ((const ushort4*)(emb16 + off_elems))[i];
                v = make_float4(bf2f(h.x), bf2f(h.y), bf2f(h.z), bf2f(h.w));
            } else {
                v = ((const float4*)((const float*)emb16 + off_elems))[i];
            }
            ((float4*)out_x0)[i] = v;
        }
    }
}

// ---------------- fused: degree histogram (blocks [0,eb)) + W-prep (blocks [eb,eb+192)) ----
// W -> MFMA B-fragment layout, split-bf16 (hi + lo residual).
// B-frag for mfma_f32_16x16x32_bf16: lane l holds W[k = ks*32 + (l>>4)*8 + e][j = c*16 + (l&15)],
// e = 0..7.  WB layout (u16): [layer][h(hi/lo)][c(8)][ks(4)][lane(64)][e(8)]  => 64 KB / layer.
__global__ void k_hw(const u32* __restrict__ ei, int E, int n,
                     const int* __restrict__ flags, int* __restrict__ hist,
                     const void* __restrict__ Wbase, u16* __restrict__ WB, int eb) {
    int bid = blockIdx.x;
    if (bid < eb) {
        int e = bid * 256 + threadIdx.x;
        if (e >= E) return;
        int d;
        if (flags[1]) d = ((const int2*)ei)[(size_t)E + e].x;  // int64: low word
        else          d = (int)ei[(size_t)E + e];
        atomicAdd(&hist[clampi(d, n)], 1);
    } else {
        int idx = (bid - eb) * 256 + threadIdx.x;  // [0, 3*16384)
        int e = idx & 7;
        int l = (idx >> 3) & 63;
        int ks = (idx >> 9) & 3;
        int c = (idx >> 11) & 7;
        int layer = idx >> 14;
        int k = ks * 32 + ((l >> 4) << 3) + e;
        int j = (c << 4) + (l & 15);
        size_t src = (size_t)layer * D * D + (size_t)k * D + j;
        float w = flags[2] ? bf2f(((const u16*)Wbase)[src]) : ((const float*)Wbase)[src];
        u16 hb = f2bf(w);
        u16 lb = f2bf(w - bf2f(hb));  // residual: Wh+Wl represents w to ~2^-17
        size_t o = (size_t)layer * 32768 + (size_t)((c * 4 + ks) * 64 + l) * 8 + e;
        WB[o] = hb;            // h=0 (hi)
        WB[o + 16384] = lb;    // h=1 (lo)
    }
}

// ======== k_sg: decoupled-lookback scan + dinv (blocks [0,nbk)) + GEMM layer0 (rest) ========
// Scan: state[b] = (flag<<30)|value; flag: 0=pending 1=partial 2=inclusive. Lookback only
// waits on EARLIER blocks -> deadlock-free under any dispatch order.
// GEMM0: Y0 = x0 @ W0, split-bf16 MFMA (R3-proven inner loop), LDS-staged B-frags.
__global__ __launch_bounds__(256) void k_sg(const int* __restrict__ hist, int n,
                                            u32* __restrict__ state,
                                            int* __restrict__ csr_off,
                                            float* __restrict__ dinv,
                                            const float* __restrict__ A0,
                                            const u16* __restrict__ WB,
                                            u32* __restrict__ Y0, int nbk) {
    __shared__ f32x4 ldsv[4096];  // 64 KB; scan blocks alias first 1 KB
    __shared__ int excl_sh;
    int t = threadIdx.x, b = blockIdx.x;
    if (b < nbk) {
        int* s = (int*)ldsv;
        int i = b * 256 + t;
        int h = (i < n) ? hist[i] : 0;
        s[t] = h;
        __syncthreads();
        for (int d2 = 1; d2 < 256; d2 <<= 1) {
            int add = (t >= d2) ? s[t - d2] : 0;
            __syncthreads();
            s[t] += add;
            __syncthreads();
        }
        int agg = s[255];
        if (t == 0) {
            if (b == 0) {
                __hip_atomic_store(&state[0], (2u << 30) | (u32)agg, __ATOMIC_RELEASE,
                                   __HIP_MEMORY_SCOPE_AGENT);
                excl_sh = 0;
            } else {
                __hip_atomic_store(&state[b], (1u << 30) | (u32)agg, __ATOMIC_RELEASE,
                                   __HIP_MEMORY_SCOPE_AGENT);
                int run = 0;
                int idx = b - 1;
                while (true) {
                    u32 v = __hip_atomic_load(&state[idx], __ATOMIC_ACQUIRE,
                                              __HIP_MEMORY_SCOPE_AGENT);
                    u32 f = v >> 30;
                    if (f == 0) {
                        __builtin_amdgcn_s_sleep(1);
                        continue;
                    }
                    run += (int)(v & 0x3fffffffu);
                    if (f == 2u) break;
                    idx--;
                }
                __hip_atomic_store(&state[b], (2u << 30) | (u32)(run + agg), __ATOMIC_RELEASE,
                                   __HIP_MEMORY_SCOPE_AGENT);
                excl_sh = run;
            }
        }
        __syncthreads();
        int excl = excl_sh;
        if (i < n) {
            csr_off[i] = excl + s[t] - h;       // global exclusive prefix
            dinv[i] = rsqrtf((float)(h + 1));   // +1 self-loop
        }
    } else {
        // ---- gemm layer 0 ----
        int tid = t;
        {
            const f32x4* src = (const f32x4*)WB;  // layer 0
#pragma unroll
            for (int i = 0; i < 16; i++) ldsv[tid + 256 * i] = src[tid + 256 * i];
        }
        __syncthreads();

        int w = tid >> 6, l = tid & 63;
        int row0 = (b - nbk) * 64 + w * 16;
        int ar = row0 + (l & 15);
        if (ar >= n) ar = 0;  // OOB rows read row 0; masked at store
        const float* Ab = A0 + (size_t)ar * D + ((l >> 4) << 3);

        f32x4 acc[8] = {};
        const short8* bp = (const short8*)ldsv;

#pragma unroll
        for (int ks = 0; ks < 4; ks++) {
            f32x4 a0 = *(const f32x4*)(Ab + ks * 32);
            f32x4 a1 = *(const f32x4*)(Ab + ks * 32 + 4);
            float av[8] = {a0.x, a0.y, a0.z, a0.w, a1.x, a1.y, a1.z, a1.w};
            short8 ah, al;
#pragma unroll
            for (int e = 0; e < 8; e++) {
                u16 h = f2bf(av[e]);
                ah[e] = (short)h;
                al[e] = (short)f2bf(av[e] - bf2f(h));
            }
#pragma unroll
            for (int c = 0; c < 8; c++) {
                short8 bh = bp[(c * 4 + ks) * 64 + l];
                short8 bl = bp[2048 + (c * 4 + ks) * 64 + l];
                acc[c] = __builtin_amdgcn_mfma_f32_16x16x32_bf16(al, bh, acc[c], 0, 0, 0);
                acc[c] = __builtin_amdgcn_mfma_f32_16x16x32_bf16(ah, bl, acc[c], 0, 0, 0);
                acc[c] = __builtin_amdgcn_mfma_f32_16x16x32_bf16(ah, bh, acc[c], 0, 0, 0);
            }
        }

        int rbase = row0 + ((l >> 4) << 2);
        int col = l & 15;
#pragma unroll
        for (int r = 0; r < 4; r++) {
            int gr = rbase + r;
            if (gr < n) {
#pragma unroll
                for (int c = 0; c < 4; c++) {
                    u32 pack = (u32)f2bf(acc[c][r]) | ((u32)f2bf(acc[c + 4][r]) << 16);
                    Y0[(size_t)gr * 64 + c * 16 + col] = pack;
                }
            }
        }
    }
}

// ================= k_sx: CSR scatter only =================
__global__ void k_sx(const u32* __restrict__ ei, int E, int n,
                     const int* __restrict__ flags,
                     const int* __restrict__ csr_off, int* __restrict__ csr_pos,
                     const float* __restrict__ dinv, int2* __restrict__ csr_pair) {
    int e = blockIdx.x * 256 + threadIdx.x;
    if (e >= E) return;
    int s, d;
    if (flags[1]) {
        s = ((const int2*)ei)[e].x;
        d = ((const int2*)ei)[(size_t)E + e].x;
    } else {
        s = (int)ei[e];
        d = (int)ei[(size_t)E + e];
    }
    s = clampi(s, n);
    d = clampi(d, n);
    int p = csr_off[d] + atomicAdd(&csr_pos[d], 1);
    if (p >= E) p = E - 1;
    csr_pair[p] = make_int2(s, __float_as_int(dinv[s] * dinv[d]));
}

// ---------------- GEMM (layers 1,2): Y = x_l @ W_l via split-bf16 MFMA ----------------
__global__ __launch_bounds__(256) void k_gemm(const float* __restrict__ A,
                                              const u16* __restrict__ WB, int layer,
                                              int n, u32* __restrict__ Y) {
    __shared__ f32x4 ldsv[4096];  // 64 KB: WB[layer] verbatim
    int tid = threadIdx.x;
    {
        const f32x4* src = (const f32x4*)(WB + (size_t)layer * 32768);
#pragma unroll
        for (int i = 0; i < 16; i++) ldsv[tid + 256 * i] = src[tid + 256 * i];
    }
    __syncthreads();

    int w = tid >> 6, l = tid & 63;
    int row0 = blockIdx.x * 64 + w * 16;
    int ar = row0 + (l & 15);
    if (ar >= n) ar = 0;  // OOB rows read row 0; masked at store
    const float* Ab = A + (size_t)ar * D + ((l >> 4) << 3);

    f32x4 acc[8] = {};
    const short8* bp = (const short8*)ldsv;

#pragma unroll
    for (int ks = 0; ks < 4; ks++) {
        f32x4 a0 = *(const f32x4*)(Ab + ks * 32);
        f32x4 a1 = *(const f32x4*)(Ab + ks * 32 + 4);
        float av[8] = {a0.x, a0.y, a0.z, a0.w, a1.x, a1.y, a1.z, a1.w};
        short8 ah, al;
#pragma unroll
        for (int e = 0; e < 8; e++) {
            u16 h = f2bf(av[e]);
            ah[e] = (short)h;
            al[e] = (short)f2bf(av[e] - bf2f(h));
        }
#pragma unroll
        for (int c = 0; c < 8; c++) {
            short8 bh = bp[(c * 4 + ks) * 64 + l];
            short8 bl = bp[2048 + (c * 4 + ks) * 64 + l];
            acc[c] = __builtin_amdgcn_mfma_f32_16x16x32_bf16(al, bh, acc[c], 0, 0, 0);
            acc[c] = __builtin_amdgcn_mfma_f32_16x16x32_bf16(ah, bl, acc[c], 0, 0, 0);
            acc[c] = __builtin_amdgcn_mfma_f32_16x16x32_bf16(ah, bh, acc[c], 0, 0, 0);
        }
    }

    int rbase = row0 + ((l >> 4) << 2);
    int col = l & 15;
#pragma unroll
    for (int r = 0; r < 4; r++) {
        int gr = rbase + r;
        if (gr < n) {
#pragma unroll
            for (int c = 0; c < 4; c++) {
                u32 pack = (u32)f2bf(acc[c][r]) | ((u32)f2bf(acc[c + 4][r]) << 16);
                Y[(size_t)gr * 64 + c * 16 + col] = pack;
            }
        }
    }
}

// ---------------- aggregation: one WAVE per dst node; 4 edges per gather instr ----------------
__global__ __launch_bounds__(256) void k_agg(const u32* __restrict__ Y,
                                             const int* __restrict__ csr_off,
                                             const int* __restrict__ cnt,
                                             const int2* __restrict__ csr_pair,
                                             const float* __restrict__ dinv,
                                             const void* __restrict__ bias_base, int layer,
                                             const int* __restrict__ flags, int n, int nD,
                                             const float* __restrict__ out_base,
                                             float* __restrict__ out_x,
                                             float* __restrict__ out_tot) {
    int i = blockIdx.x * 4 + (threadIdx.x >> 6);
    if (i >= n) return;
    int t = threadIdx.x & 63;
    int g = t >> 4, p = t & 15;

    float lo0 = 0.f, lo1 = 0.f, lo2 = 0.f, lo3 = 0.f;
    float hi0 = 0.f, hi1 = 0.f, hi2 = 0.f, hi3 = 0.f;

#define ACC4(V, W)                                                       \
    do {                                                                 \
        lo0 += __uint_as_float((V).x << 16) * (W);                       \
        hi0 += __uint_as_float((V).x & 0xffff0000u) * (W);               \
        lo1 += __uint_as_float((V).y << 16) * (W);                       \
        hi1 += __uint_as_float((V).y & 0xffff0000u) * (W);               \
        lo2 += __uint_as_float((V).z << 16) * (W);                       \
        hi2 += __uint_as_float((V).z & 0xffff0000u) * (W);               \
        lo3 += __uint_as_float((V).w << 16) * (W);                       \
        hi3 += __uint_as_float((V).w & 0xffff0000u) * (W);               \
    } while (0)

    float di = dinv[i];
    {
        uint4 vs = *(const uint4*)(Y + (size_t)i * 64 + p * 4);
        float ws = (g == 0) ? di * di : 0.0f;
        ACC4(vs, ws);
    }

    int start = csr_off[i];
    int c = cnt[i];

    for (int base = 0; base < c; base += 64) {
        int m = c - base;
        if (m > 64) m = 64;
        int2 pr = (t < m) ? csr_pair[start + base + t] : make_int2(0, 0);
        int s0 = __shfl(pr.x, g);
        float w0 = __uint_as_float((u32)__shfl(pr.y, g));
        uint4 v0 = *(const uint4*)(Y + (size_t)s0 * 64 + p * 4);
        for (int j = 4; j < m; j += 4) {
            int s1 = __shfl(pr.x, j + g);
            float w1 = __uint_as_float((u32)__shfl(pr.y, j + g));
            uint4 v1 = *(const uint4*)(Y + (size_t)s1 * 64 + p * 4);
            ACC4(v0, w0);
            v0 = v1;
            w0 = w1;
        }
        ACC4(v0, w0);
    }
#undef ACC4

#pragma unroll
    for (int mask = 16; mask <= 32; mask <<= 1) {
        lo0 += __shfl_xor(lo0, mask);
        lo1 += __shfl_xor(lo1, mask);
        lo2 += __shfl_xor(lo2, mask);
        lo3 += __shfl_xor(lo3, mask);
        hi0 += __shfl_xor(hi0, mask);
        hi1 += __shfl_xor(hi1, mask);
        hi2 += __shfl_xor(hi2, mask);
        hi3 += __shfl_xor(hi3, mask);
    }

    if (g < 2) {  // g==0: dims 4p..4p+3 ; g==1: dims 64+4p..64+4p+3
        float r0 = g ? hi0 : lo0;
        float r1 = g ? hi1 : lo1;
        float r2 = g ? hi2 : lo2;
        float r3 = g ? hi3 : lo3;
        int off = g * 64 + 4 * p;
        float b0, b1, b2, b3;
        if (flags[0]) {
            const u16* bb = (const u16*)bias_base + layer * D + off;
            ushort4 h = *(const ushort4*)bb;
            b0 = bf2f(h.x); b1 = bf2f(h.y); b2 = bf2f(h.z); b3 = bf2f(h.w);
        } else {
            const float* bb = (const float*)bias_base + layer * D + off;
            float4 f = *(const float4*)bb;
            b0 = f.x; b1 = f.y; b2 = f.z; b3 = f.w;
        }
        float4 xv = make_float4(r0 + b0, r1 + b1, r2 + b2, r3 + b3);
        size_t base = (size_t)i * D + off;
        *(float4*)&out_x[base] = xv;

        if (out_tot) {  // layer 2: fuse total = x0+x1+x2+x3
            float4 s0 = *(const float4*)&out_base[(size_t)1 * nD + base];
            float4 s1 = *(const float4*)&out_base[(size_t)2 * nD + base];
            float4 s2 = *(const float4*)&out_base[(size_t)3 * nD + base];
            *(float4*)&out_tot[base] =
                make_float4(s0.x + s1.x + s2.x + xv.x, s0.y + s1.y + s2.y + xv.y,
                            s0.z + s1.z + s2.z + xv.z, s0.w + s1.w + s2.w + xv.w);
        }
    }
}

extern "C" void kernel_launch(void* const* d_in, const int* in_sizes, int n_in,
                              void* d_out, int out_size, void* d_ws, size_t ws_size,
                              hipStream_t stream) {
    float* out = (float*)d_out;              // fp32: [total, x0, x1, x2, x3]

    const int n = out_size / (5 * D);        // 50000

    // inputs identified by element count (robust to ordering)
    int i_emb = -1, i_ei = -1, i_w = -1, i_b = -1;
    {
        int order[8];
        int m = n_in > 8 ? 8 : n_in;
        for (int i = 0; i < m; i++) order[i] = i;
        for (int a = 0; a < m; a++)
            for (int b2 = a + 1; b2 < m; b2++)
                if (in_sizes[order[b2]] > in_sizes[order[a]]) {
                    int tmp = order[a]; order[a] = order[b2]; order[b2] = tmp;
                }
        i_emb = order[0];
        i_ei  = (m > 1) ? order[1] : 0;
        for (int i = 0; i < m; i++) {
            if (in_sizes[i] == 3 * D * D && i_w < 0) i_w = i;
            if (in_sizes[i] == 3 * D && i_b < 0) i_b = i;
        }
        if (i_w < 0) i_w = (m > 2) ? order[2] : 0;
        if (i_b < 0) i_b = (m > 3) ? order[3] : 0;
    }
    const void* emb  = d_in[i_emb];
    const void* wts  = d_in[i_w];
    const void* bias = d_in[i_b];
    const u32*  ei   = (const u32*)d_in[i_ei];

    const int E = in_sizes[i_ei] / 2;        // 600000
    const int rows = in_sizes[i_emb] / D;    // 80000
    const int off_elems = (rows - n) * D;

    char* p = (char*)d_ws;
    auto take = [&](size_t bytes) {
        char* r = p;
        p += (bytes + 255) & ~(size_t)255;
        return r;
    };
    const int nD = n * D;
    const int nb = (n + 255) / 256;          // 196
    const int eb = (E + 255) / 256;
    const int x0b = (nD / 4 + 255) / 256;
    const int gb = (n + 63) / 64;
    const int ab = (n + 3) / 4;              // 4 nodes (waves) per 256-thr block

    int*   flags    = (int*)  take(3 * 4);
    int*   hist     = (int*)  take((size_t)n * 4);
    int*   csr_pos  = (int*)  take((size_t)n * 4);
    int*   csr_off  = (int*)  take((size_t)n * 4);
    u32*   state    = (u32*)  take((size_t)nb * 4);
    float* dinv     = (float*)take((size_t)n * 4);
    int2*  csr_pair = (int2*) take((size_t)E * 8);
    u32*   ybuf     = (u32*)  take((size_t)n * 64 * 4);   // bf16-packed Y
    u16*   wb       = (u16*)  take((size_t)3 * 32768 * 2); // W in MFMA B-frag layout (hi+lo)

    float* x0 = out + (size_t)nD;

    // 1: zeros + flags + x0 copy
    k_init<<<nb + x0b, 256, 0, stream>>>(hist, csr_pos, state, n, nb, (const u16*)emb,
                                         ei, (const u16*)wts, flags, off_elems, nD / 4, x0);
    // 2: degree hist + W-prep
    k_hw<<<eb + 192, 256, 0, stream>>>(ei, E, n, flags, hist, wts, wb, eb);
    // 3: lookback scan (+dinv) with gemm layer-0 hidden behind it
    k_sg<<<nb + gb, 256, 0, stream>>>(hist, n, state, csr_off, dinv, x0, wb, ybuf, nb);
    // 4: CSR scatter
    k_sx<<<eb, 256, 0, stream>>>(ei, E, n, flags, csr_off, csr_pos, dinv, csr_pair);

    // 5..9: agg_l (+ gemm_{l+1} for l<2)
    for (int l = 0; l < 3; l++) {
        float* ox = out + (size_t)(2 + l) * nD;        // x_{l+1} slot
        k_agg<<<ab, 256, 0, stream>>>(ybuf, csr_off, hist, csr_pair, dinv, bias, l,
                                      flags, n, nD, out, ox,
                                      (l == 2) ? out : (float*)nullptr);
        if (l < 2) {
            k_gemm<<<gb, 256, 0, stream>>>(ox, wb, l + 1, n, ybuf);
        }
    }
}